// Round 8
// baseline (306.561 us; speedup 1.0000x reference)
//
#include <hip/hip_runtime.h>

// CentroidPool: N=65536 x K=4096 x D=128 fp32 -> argmin_k ||x - c_k|| (int32).
// ROUND-21: MFMA shape 16x16x32 -> 32x32x16 (f16x3-split preserved).
//   Scheduler axis exhausted (r18 setprio +5%, r19 weave spilled, r20 stagger
//   neutral): residual is per-wave instruction overhead. 32x32x16 at the same
//   register budget (accs 2x16, B ping-pong 2x16, trackers 32):
//   - MFMA floor 99.4 -> 86.6us (measured ceilings 2075 vs 2382 TF)
//   - MFMA instruction count /4 per cent-k (issue pressure)
//   - ds_read per cent /4 (A-fragment reused across 32 cols)
//   - INS + acc-init VALU per cent /2 (64 cents/iter, one 16-slot INS pass)
//   Wave tile: 32 points x 64 cents/iter, 16 iters; block = 4 waves x MB=32
//   points; C/D layout col=lane&31, row=(reg&3)+8*(reg>>2)+4*(lane>>5) (m74).
//   B pre-packed per (wave,iter,kstep,colgroup): every load 64x16B coalesced.
// Stage 2: exact fp64 rescore of the 2 candidates (near-tie rescue).

typedef _Float16 f16;
typedef f16  f16x8  __attribute__((ext_vector_type(8)));
typedef float f32x16 __attribute__((ext_vector_type(16)));

constexpr int N_PTS  = 65536;
constexpr int K_CENT = 4096;
constexpr int D_DIM  = 128;
constexpr int MB     = 32;     // points per block (4 waves share them)
constexpr int KW     = 1024;   // centroids per wave (waves split K 4-ways)
constexpr float SOFF = 256.0f; // score offset => strictly positive scores

// ---------------------------------------------------------------------------
// Split coords to f16 h/l, pack into 32x32x16 B-fragment order, compute c2.
// Element (cent, dim): w = cent>>10, i = (cent>>6)&15, cg = (cent>>5)&1,
//   col = cent&31; s = dim>>4, hi = (dim>>3)&1, j = dim&7; lane = hi*32+col.
// dst = w*131072 + i*8192 + s*1024 + cg*512 + lane*8 + j.
// A wave's (i,s,cg) fragment = 512 contiguous f16 = 64 lanes x 16B? (1024B);
// pair (cg0,cg1) = 1024 f16 loaded as two 16B lane-loads at +0 / +512.
// ---------------------------------------------------------------------------
__global__ __launch_bounds__(256) void split_pack_c2(const float* __restrict__ c,
                                                     f16* __restrict__ chp,
                                                     f16* __restrict__ clp,
                                                     float* __restrict__ c2b) {
    __shared__ float part[4];
    const int t = threadIdx.x;
    const int e = blockIdx.x * 256 + t;       // K*D source elements
    const int cent = e >> 7, dim = e & 127;
    float x = c[e];
    f16 h = (f16)x;
    f16 l = (f16)(x - (float)h);
    int w = cent >> 10, i = (cent >> 6) & 15, cg = (cent >> 5) & 1, col = cent & 31;
    int s = dim >> 4, hi = (dim >> 3) & 1, j = dim & 7;
    int lane = hi * 32 + col;
    int dst = w * 131072 + i * 8192 + s * 1024 + cg * 512 + lane * 8 + j;
    chp[dst] = h;
    clp[dst] = l;
    // c2 reduction: each wave sums its 64 dims, two waves per cent.
    float s2 = x * x;
#pragma unroll
    for (int m = 1; m < 64; m <<= 1) s2 += __shfl_xor(s2, m, 64);
    if ((t & 63) == 0) part[t >> 6] = s2;
    __syncthreads();
    if (t < 2) c2b[blockIdx.x * 2 + t] = part[2 * t] + part[2 * t + 1] + SOFF;
}

// ---------------------------------------------------------------------------
// Stage 1. Block = 4 waves x 32 points; latent (-2x) split h/l in XOR-swizzled
// LDS. Wave w scans cents [w*1024,(w+1)*1024) as 16 iters x 64 cents
// (2 col-groups of 32). Per kstep (K=16): A = latent rows 0..31 (row=lane&31,
// k=(lane>>5)*8+j from LDS b128), B = packed global (ping-pong Ba/Bb).
// acc0/acc1 (f32x16) = col-groups 0/1; C/D row=(reg&3)+8*(reg>>2)+4*(lane>>5).
// key = (bits(score)&~31)|kn, kn = i*2+cg (5b); cent=((wave*32+kn)<<5)|col.
// ---------------------------------------------------------------------------
__global__ __launch_bounds__(256, 2) void argmin_mfma(
        const float* __restrict__ latent,
        const f16*   __restrict__ chp,    // packed B hi
        const f16*   __restrict__ clp,    // packed B lo
        const float* __restrict__ c2b,
        int* __restrict__ top1,
        int* __restrict__ top2) {
    __shared__ f16 latH[MB * 128];
    __shared__ f16 latL[MB * 128];
    __shared__ unsigned r1K[4][MB]; __shared__ int r1I[4][MB];
    __shared__ unsigned r2K[4][MB]; __shared__ int r2I[4][MB];

    const int t    = threadIdx.x;
    const int wave = t >> 6;
    const int lane = t & 63;
    const int ln5  = lane & 31;    // A row / B col / C-D col
    const int hi   = lane >> 5;    // k-half selector
    const int l15  = lane & 15;
    const int row0 = blockIdx.x * MB;

    {   // Stage latent 32x128: scale -2, split h/l, XOR-swizzle 16-B units.
        const float4* src = (const float4*)(latent + (size_t)row0 * D_DIM);
#pragma unroll
        for (int i = 0; i < 2; ++i) {
            int g  = i * 256 + t;          // float8 index in [0,512)
            int r  = g >> 4;               // row (16 float8 per row), 0..31
            int c8 = g & 15;               // logical 16-B column
            float4 v0 = src[2 * g];
            float4 v1 = src[2 * g + 1];
            float xs[8] = {v0.x, v0.y, v0.z, v0.w, v1.x, v1.y, v1.z, v1.w};
            f16x8 hv, lv;
#pragma unroll
            for (int c = 0; c < 8; ++c) {
                float x = -2.0f * xs[c];
                f16 h = (f16)x;
                hv[c] = h;
                lv[c] = (f16)(x - (float)h);
            }
            int pc = ((c8 ^ (r & 15)) << 3);
            *(f16x8*)&latH[r * 128 + pc] = hv;
            *(f16x8*)&latL[r * 128 + pc] = lv;
        }
    }
    __syncthreads();

    unsigned b1[16], b2[16];
#pragma unroll
    for (int i = 0; i < 16; ++i) { b1[i] = 0xFFFFFFFFu; b2[i] = 0xFFFFFFFFu; }

    const int wbase = wave * KW;
    // Packed-B element offset: (i,s) at baseB + i*8192 + s*1024 (+512 for cg1).
    unsigned offB = (unsigned)(wave * 131072) + (unsigned)(lane * 8);

    // Named ping-pong regs — never address-taken.
    f16x8 Ba0, Ba1, Ba2, Ba3, Bb0, Bb1, Bb2, Bb3;
    f32x16 a0, a1;

#define PFB(P, off) \
    P##0 = *(const f16x8*)(chp + (off)); \
    P##1 = *(const f16x8*)(clp + (off)); \
    P##2 = *(const f16x8*)(chp + (off) + 512); \
    P##3 = *(const f16x8*)(clp + (off) + 512);

#define MF(d, a, b) d = __builtin_amdgcn_mfma_f32_32x32x16_f16(a, b, d, 0, 0, 0);

// kstep: 6 MFMAs (3 splits x 2 col-groups), dependent-same-acc distance 2.
// Prio 1 across the cluster (T5; kept from r18, +5%).
#define STEP(P, s) { \
    __builtin_amdgcn_s_setprio(1); \
    const int pc_ = ((((s) << 1) + hi) ^ l15) << 3; \
    f16x8 ah_ = *(const f16x8*)&latH[ln5 * 128 + pc_]; \
    f16x8 al_ = *(const f16x8*)&latL[ln5 * 128 + pc_]; \
    MF(a0, ah_, P##0) MF(a1, ah_, P##2) \
    MF(a0, ah_, P##1) MF(a1, ah_, P##3) \
    MF(a0, al_, P##0) MF(a1, al_, P##2) \
    __builtin_amdgcn_s_setprio(0); }

// Merged dual-key top-2 insert: exact top-2 of {b1,b2,kA,kB}. Mask ~31 (5b kn).
#define INS2(sA, sB, slot) { \
    unsigned kA_ = (__float_as_uint(sA) & 0xFFFFFFE0u) | kn0; \
    unsigned kB_ = (__float_as_uint(sB) & 0xFFFFFFE0u) | kn1; \
    unsigned lo_ = kA_ < kB_ ? kA_ : kB_; \
    unsigned hi_ = kA_ < kB_ ? kB_ : kA_; \
    unsigned ob1_ = b1[slot]; \
    unsigned mx_ = ob1_ < lo_ ? lo_ : ob1_; \
    unsigned t2_ = mx_ < hi_ ? mx_ : hi_; \
    b1[slot] = ob1_ < lo_ ? ob1_ : lo_; \
    b2[slot] = t2_ < b2[slot] ? t2_ : b2[slot]; }

    // Prime: load (i=0, s=0) into Ba.
    PFB(Ba, offB)
    float cv0 = c2b[wbase + ln5];
    float cv1 = c2b[wbase + 32 + ln5];

#pragma unroll 1
    for (int i = 0; i < 16; ++i) {
        // Direct acc init from c2 (per-lane col value broadcast over 16 rows).
#pragma unroll
        for (int r = 0; r < 16; ++r) { a0[r] = cv0; a1[r] = cv1; }

        int ni = (i + 1) & 15;      // wraps at end; value then unused
        float cvn0 = c2b[wbase + ni * 64 + ln5];
        float cvn1 = c2b[wbase + ni * 64 + 32 + ln5];

        PFB(Bb, offB + 1024) STEP(Ba, 0)
        PFB(Ba, offB + 2048) STEP(Bb, 1)
        PFB(Bb, offB + 3072) STEP(Ba, 2)
        PFB(Ba, offB + 4096) STEP(Bb, 3)
        PFB(Bb, offB + 5120) STEP(Ba, 4)
        PFB(Ba, offB + 6144) STEP(Bb, 5)
        PFB(Bb, offB + 7168) STEP(Ba, 6)
        if (i != 15) { PFB(Ba, offB + 8192) }   // next iter (i+1, s=0)
        STEP(Bb, 7)

        const unsigned kn0 = (unsigned)(i * 2);
        const unsigned kn1 = kn0 + 1u;
#pragma unroll
        for (int r = 0; r < 16; ++r) { INS2(a0[r], a1[r], r) }

        cv0 = cvn0; cv1 = cvn1; offB += 8192;
    }

    // Butterfly across the 32 cent-columns (5 steps); writer col==0 per k-half.
#pragma unroll
    for (int r = 0; r < 16; ++r) {
        unsigned k1 = b1[r], k2 = b2[r];
        int i1 = ((wave * 32 + (int)(k1 & 31u)) << 5) | ln5;
        int i2 = ((wave * 32 + (int)(k2 & 31u)) << 5) | ln5;
#pragma unroll
        for (int msk = 1; msk < 32; msk <<= 1) {
            unsigned ok1 = (unsigned)__shfl_xor((int)k1, msk, 64);
            int      oi1 = __shfl_xor(i1, msk, 64);
            unsigned ok2 = (unsigned)__shfl_xor((int)k2, msk, 64);
            int      oi2 = __shfl_xor(i2, msk, 64);
            bool ow = ok1 < k1;
            unsigned w1k = ow ? ok1 : k1; int w1i = ow ? oi1 : i1;
            unsigned lsk = ow ? k1 : ok1; int lsi = ow ? i1 : oi1;
            unsigned wsk = ow ? ok2 : k2; int wsi = ow ? oi2 : i2;
            bool sw = lsk < wsk;
            k1 = w1k; i1 = w1i;
            k2 = sw ? lsk : wsk; i2 = sw ? lsi : wsi;
        }
        if (ln5 == 0) {
            int p = (r & 3) + 8 * (r >> 2) + 4 * hi;   // C/D row of this reg
            r1K[wave][p] = k1; r1I[wave][p] = i1;
            r2K[wave][p] = k2; r2I[wave][p] = i2;
        }
    }
    __syncthreads();

    if (t < MB) {
        unsigned k1 = r1K[0][t], k2 = r2K[0][t];
        int      i1 = r1I[0][t], i2 = r2I[0][t];
#pragma unroll
        for (int w = 1; w < 4; ++w) {
            unsigned ok1 = r1K[w][t], ok2 = r2K[w][t];
            int      oi1 = r1I[w][t], oi2 = r2I[w][t];
            bool ow = ok1 < k1;
            unsigned w1k = ow ? ok1 : k1; int w1i = ow ? oi1 : i1;
            unsigned lsk = ow ? k1 : ok1; int lsi = ow ? i1 : oi1;
            unsigned wsk = ow ? ok2 : k2; int wsi = ow ? oi2 : i2;
            bool sw = lsk < wsk;
            k1 = w1k; i1 = w1i;
            k2 = sw ? lsk : wsk; i2 = sw ? lsi : wsi;
        }
        top1[row0 + t] = i1;
        top2[row0 + t] = i2;
    }
}

// ---------------------------------------------------------------------------
// Stage 2: exact fp64 rescore of the two candidates; true winner wins
// (idx tie -> smaller index).
// ---------------------------------------------------------------------------
__global__ __launch_bounds__(256) void rescore(const float* __restrict__ latent,
                                               const float* __restrict__ coords,
                                               const int* __restrict__ top1,
                                               const int* __restrict__ top2,
                                               int* __restrict__ out) {
    int n = blockIdx.x * 256 + threadIdx.x;
    int i1 = top1[n], i2 = top2[n];
    const float* x  = latent + (size_t)n * D_DIM;
    const float* ca = coords + (size_t)i1 * D_DIM;
    const float* cb = coords + (size_t)i2 * D_DIM;
    double d1 = 0.0, d2 = 0.0;
#pragma unroll
    for (int d = 0; d < D_DIM; d += 4) {
        float4 xv = *(const float4*)(x + d);
        float4 av = *(const float4*)(ca + d);
        float4 bv = *(const float4*)(cb + d);
        double e;
        e = (double)xv.x - (double)av.x; d1 += e * e;
        e = (double)xv.y - (double)av.y; d1 += e * e;
        e = (double)xv.z - (double)av.z; d1 += e * e;
        e = (double)xv.w - (double)av.w; d1 += e * e;
        e = (double)xv.x - (double)bv.x; d2 += e * e;
        e = (double)xv.y - (double)bv.y; d2 += e * e;
        e = (double)xv.z - (double)bv.z; d2 += e * e;
        e = (double)xv.w - (double)bv.w; d2 += e * e;
    }
    bool second = (d2 < d1) || (d2 == d1 && i2 < i1);
    out[n] = second ? i2 : i1;
}

// ---------------------------------------------------------------------------
extern "C" void kernel_launch(void* const* d_in, const int* in_sizes, int n_in,
                              void* d_out, int out_size, void* d_ws, size_t ws_size,
                              hipStream_t stream) {
    const float* latent = (const float*)d_in[0];
    const float* coords = (const float*)d_in[1];
    int* out = (int*)d_out;

    // ws: chp [K*D] f16 | clp [K*D] f16 | c2b [K] f32 | top1 [N] | top2 [N]
    f16*   chp = (f16*)d_ws;
    f16*   clp = chp + (size_t)K_CENT * D_DIM;
    float* c2b = (float*)(clp + (size_t)K_CENT * D_DIM);
    int*   t1  = (int*)(c2b + K_CENT);
    int*   t2  = t1 + N_PTS;

    split_pack_c2<<<dim3(K_CENT * D_DIM / 256), dim3(256), 0, stream>>>(coords, chp, clp, c2b);
    argmin_mfma<<<dim3(N_PTS / MB), dim3(256), 0, stream>>>(latent, chp, clp, c2b, t1, t2);
    rescore<<<dim3(N_PTS / 256), dim3(256), 0, stream>>>(latent, coords, t1, t2, out);
}

// Round 9
// 238.416 us; speedup vs baseline: 1.2858x; 1.2858x over previous
//
#include <hip/hip_runtime.h>

// CentroidPool: N=65536 x K=4096 x D=128 fp32 -> argmin_k ||x - c_k|| (int32).
// Stage 1: f16x3-split MFMA GEMM (xh*ch + xh*cl + xl*ch, fp32 acc = c2 init),
//   top-2 via sortable packed keys, register ping-pong B pipeline, B pre-packed
//   in per-(tile,step,lane) fragment order -> every B load 64x16B coalesced.
// ROUND-22: revert r21 shape experiment (32x32x16: only 2 acc dep-chains ->
//   ~60us MFMA stall, 230us). Back to the r18 16x16x32 body (167.7us, busy-
//   packed: MFMA 97us + VALU 74us ~= wall). New: the fp64 top-2 RESCORE IS
//   FUSED into the argmin epilogue (thread t<64 already holds i1,i2; latent
//   row L2-hot, coords L3-resident) -- deletes the 3rd dispatch, its 33.5MB
//   latent HBM re-read, and the top1/top2 global round-trip. ~75us of each
//   iteration was outside argmin; this targets the biggest chunk of it.
// Output written directly by argmin blocks.

typedef _Float16 f16;
typedef f16  f16x8 __attribute__((ext_vector_type(8)));
typedef float f32x4 __attribute__((ext_vector_type(4)));

constexpr int N_PTS  = 65536;
constexpr int K_CENT = 4096;
constexpr int D_DIM  = 128;
constexpr int MB     = 64;     // points per block (4 waves share them)
constexpr int KW     = 1024;   // centroids per wave (waves split K 4-ways)
constexpr float SOFF = 256.0f; // score offset => strictly positive scores

// ---------------------------------------------------------------------------
// Split coords to f16 h/l AND pack into fragment order, AND compute c2+SOFF.
// dst = ((gt*4 + ds)*2 + n)*512 + lane*8 + j
//   cent = gt*32 + n*16 + l15, dim = ds*32 + quad*8 + j, lane = quad*16 + l15.
// Block = 256 threads = 2 cents x 128 dims; waves 0,1 -> cent0, 2,3 -> cent1.
// ---------------------------------------------------------------------------
__global__ __launch_bounds__(256) void split_pack_c2(const float* __restrict__ c,
                                                     f16* __restrict__ chp,
                                                     f16* __restrict__ clp,
                                                     float* __restrict__ c2b) {
    __shared__ float part[4];
    const int t = threadIdx.x;
    const int e = blockIdx.x * 256 + t;       // K*D source elements
    const int cent = e >> 7, dim = e & 127;
    float x = c[e];
    f16 h = (f16)x;
    f16 l = (f16)(x - (float)h);
    int gt = cent >> 5, n = (cent >> 4) & 1, l15 = cent & 15;
    int ds = dim >> 5, quad = (dim >> 3) & 3, j = dim & 7;
    int lane = quad * 16 + l15;
    int dst = ((gt * 4 + ds) * 2 + n) * 512 + lane * 8 + j;
    chp[dst] = h;
    clp[dst] = l;
    // c2 reduction: each wave sums its 64 dims, two waves per cent.
    float s = x * x;
#pragma unroll
    for (int m = 1; m < 64; m <<= 1) s += __shfl_xor(s, m, 64);
    if ((t & 63) == 0) part[t >> 6] = s;
    __syncthreads();
    if (t < 2) c2b[blockIdx.x * 2 + t] = part[2 * t] + part[2 * t + 1] + SOFF;
}

// ---------------------------------------------------------------------------
// Stage 1 + fused rescore. Block = 4 waves x 64 points; latent (-2x) split h/l
// in XOR-swizzled LDS. Wave w scans cents [w*1024,(w+1)*1024) in 32-wide
// k-tiles (2 n-groups). Ping-pong invariant: Ba = (kt, ds0), offB -> (kt,ds1).
// key = (bits(score)&~63)|kn, kn = kt*2+n (6b); cent = (wave*64+kn)*16 + l15.
// Epilogue: thread t<64 holds the block-wide top-2 for point row0+t and does
// the exact fp64 rescore inline (tie -> smaller index), writing out directly.
// ---------------------------------------------------------------------------
__global__ __launch_bounds__(256, 2) void argmin_mfma(
        const float* __restrict__ latent,
        const float* __restrict__ coords,
        const f16*   __restrict__ chp,    // packed B hi
        const f16*   __restrict__ clp,    // packed B lo
        const float* __restrict__ c2b,
        int* __restrict__ out) {
    __shared__ f16 latH[MB * 128];
    __shared__ f16 latL[MB * 128];
    __shared__ unsigned r1K[4][MB]; __shared__ int r1I[4][MB];
    __shared__ unsigned r2K[4][MB]; __shared__ int r2I[4][MB];

    const int t    = threadIdx.x;
    const int wave = t >> 6;
    const int lane = t & 63;
    const int quad = lane >> 4;
    const int l15  = lane & 15;
    const int row0 = blockIdx.x * MB;

    {   // Stage latent: scale -2, split h/l, XOR-swizzle 16-B units.
        const float4* src = (const float4*)(latent + (size_t)row0 * D_DIM);
#pragma unroll
        for (int i = 0; i < 4; ++i) {
            int g  = i * 256 + t;          // float8 index in [0,1024)
            int r  = g >> 4;               // row (16 float8 per row)
            int c8 = g & 15;               // logical 16-B column
            float4 v0 = src[2 * g];
            float4 v1 = src[2 * g + 1];
            float xs[8] = {v0.x, v0.y, v0.z, v0.w, v1.x, v1.y, v1.z, v1.w};
            f16x8 hv, lv;
#pragma unroll
            for (int c = 0; c < 8; ++c) {
                float x = -2.0f * xs[c];
                f16 h = (f16)x;
                hv[c] = h;
                lv[c] = (f16)(x - (float)h);
            }
            int pc = ((c8 ^ (r & 15)) << 3);
            *(f16x8*)&latH[r * 128 + pc] = hv;
            *(f16x8*)&latL[r * 128 + pc] = lv;
        }
    }
    __syncthreads();

    unsigned b1[16], b2[16];
#pragma unroll
    for (int i = 0; i < 16; ++i) { b1[i] = 0xFFFFFFFFu; b2[i] = 0xFFFFFFFFu; }

    const int wbase = wave * KW;
    // Packed-B element offset of the next step's load: uniform +1024/step.
    unsigned offB = (unsigned)(wave * 32 * 4) * 1024u + (unsigned)(lane * 8);

    // Named ping-pong regs — never address-taken.
    f16x8 Ba0, Ba1, Ba2, Ba3, Bb0, Bb1, Bb2, Bb3;
    f32x4 a00, a01, a10, a11, a20, a21, a30, a31;

#define PFB(P) \
    P##0 = *(const f16x8*)(chp + offB); \
    P##1 = *(const f16x8*)(clp + offB); \
    P##2 = *(const f16x8*)(chp + offB + 512); \
    P##3 = *(const f16x8*)(clp + offB + 512);

#define MF(d, a, b) d = __builtin_amdgcn_mfma_f32_16x16x32_f16(a, b, d, 0, 0, 0);
#define MFC(d, a, b, c) d = __builtin_amdgcn_mfma_f32_16x16x32_f16(a, b, c, 0, 0, 0);

// ds>=1 step: accumulate into live accs. Prio 1 across the MFMA cluster.
#define STEP(P, ds) { \
    __builtin_amdgcn_s_setprio(1); \
    const int pc_ = ((((ds) << 2) + quad) ^ l15) << 3; \
    f16x8 ah_, al_; \
    ah_ = *(const f16x8*)&latH[(     l15) * 128 + pc_]; \
    al_ = *(const f16x8*)&latL[(     l15) * 128 + pc_]; \
    MF(a00, ah_, P##0) MF(a00, ah_, P##1) MF(a00, al_, P##0) \
    MF(a01, ah_, P##2) MF(a01, ah_, P##3) MF(a01, al_, P##2) \
    ah_ = *(const f16x8*)&latH[(16 + l15) * 128 + pc_]; \
    al_ = *(const f16x8*)&latL[(16 + l15) * 128 + pc_]; \
    MF(a10, ah_, P##0) MF(a10, ah_, P##1) MF(a10, al_, P##0) \
    MF(a11, ah_, P##2) MF(a11, ah_, P##3) MF(a11, al_, P##2) \
    ah_ = *(const f16x8*)&latH[(32 + l15) * 128 + pc_]; \
    al_ = *(const f16x8*)&latL[(32 + l15) * 128 + pc_]; \
    MF(a20, ah_, P##0) MF(a20, ah_, P##1) MF(a20, al_, P##0) \
    MF(a21, ah_, P##2) MF(a21, ah_, P##3) MF(a21, al_, P##2) \
    ah_ = *(const f16x8*)&latH[(48 + l15) * 128 + pc_]; \
    al_ = *(const f16x8*)&latL[(48 + l15) * 128 + pc_]; \
    MF(a30, ah_, P##0) MF(a30, ah_, P##1) MF(a30, al_, P##0) \
    MF(a31, ah_, P##2) MF(a31, ah_, P##3) MF(a31, al_, P##2) \
    __builtin_amdgcn_s_setprio(0); }

// ds==0 step: each acc's FIRST MFMA takes the c2 broadcast as C (no INIT pass).
#define STEP0(P) { \
    __builtin_amdgcn_s_setprio(1); \
    const int pc_ = (quad ^ l15) << 3; \
    f16x8 ah_, al_; \
    ah_ = *(const f16x8*)&latH[(     l15) * 128 + pc_]; \
    al_ = *(const f16x8*)&latL[(     l15) * 128 + pc_]; \
    MFC(a00, ah_, P##0, cvec0) MF(a00, ah_, P##1) MF(a00, al_, P##0) \
    MFC(a01, ah_, P##2, cvec1) MF(a01, ah_, P##3) MF(a01, al_, P##2) \
    ah_ = *(const f16x8*)&latH[(16 + l15) * 128 + pc_]; \
    al_ = *(const f16x8*)&latL[(16 + l15) * 128 + pc_]; \
    MFC(a10, ah_, P##0, cvec0) MF(a10, ah_, P##1) MF(a10, al_, P##0) \
    MFC(a11, ah_, P##2, cvec1) MF(a11, ah_, P##3) MF(a11, al_, P##2) \
    ah_ = *(const f16x8*)&latH[(32 + l15) * 128 + pc_]; \
    al_ = *(const f16x8*)&latL[(32 + l15) * 128 + pc_]; \
    MFC(a20, ah_, P##0, cvec0) MF(a20, ah_, P##1) MF(a20, al_, P##0) \
    MFC(a21, ah_, P##2, cvec1) MF(a21, ah_, P##3) MF(a21, al_, P##2) \
    ah_ = *(const f16x8*)&latH[(48 + l15) * 128 + pc_]; \
    al_ = *(const f16x8*)&latL[(48 + l15) * 128 + pc_]; \
    MFC(a30, ah_, P##0, cvec0) MF(a30, ah_, P##1) MF(a30, al_, P##0) \
    MFC(a31, ah_, P##2, cvec1) MF(a31, ah_, P##3) MF(a31, al_, P##2) \
    __builtin_amdgcn_s_setprio(0); }

// Merged dual-key top-2 insert: exact top-2 of {b1,b2,kA,kB}.
// b1' = min(b1,lo); b2' = min(min(max(b1,lo),hi),b2)  [v_min3-fusable].
#define INS2(sA, sB, slot) { \
    unsigned kA_ = (__float_as_uint(sA) & 0xFFFFFFC0u) | kn0; \
    unsigned kB_ = (__float_as_uint(sB) & 0xFFFFFFC0u) | kn1; \
    unsigned lo_ = kA_ < kB_ ? kA_ : kB_; \
    unsigned hi_ = kA_ < kB_ ? kB_ : kA_; \
    unsigned ob1_ = b1[slot]; \
    unsigned mx_ = ob1_ < lo_ ? lo_ : ob1_; \
    unsigned t2_ = mx_ < hi_ ? mx_ : hi_; \
    b1[slot] = ob1_ < lo_ ? ob1_ : lo_; \
    b2[slot] = t2_ < b2[slot] ? t2_ : b2[slot]; }

#define INSP(A0, A1, m) \
    INS2(A0[0], A1[0], (m) * 4 + 0) INS2(A0[1], A1[1], (m) * 4 + 1) \
    INS2(A0[2], A1[2], (m) * 4 + 2) INS2(A0[3], A1[3], (m) * 4 + 3)

    // Prime: load (kt=0, ds=0) into Ba; offB -> (0, ds1).
    PFB(Ba)
    offB += 1024;
    float cv0 = c2b[wbase + l15];
    float cv1 = c2b[wbase + 16 + l15];

#pragma unroll 1
    for (int kt = 0; kt < KW / 32; ++kt) {
        f32x4 cvec0 = (f32x4){cv0, cv0, cv0, cv0};
        f32x4 cvec1 = (f32x4){cv1, cv1, cv1, cv1};

        int ktn = (kt + 1) & 31;    // wraps at end; value then unused
        float cvn0 = c2b[wbase + ktn * 32 + l15];
        float cvn1 = c2b[wbase + ktn * 32 + 16 + l15];

        PFB(Bb) offB += 1024; STEP0(Ba)     // loads (kt,ds1); C-init from cvec
        PFB(Ba) offB += 1024; STEP(Bb, 1)   // loads (kt,ds2)
        PFB(Bb) offB += 1024; STEP(Ba, 2)   // loads (kt,ds3); offB -> (kt+1,ds0)
        if (kt != KW / 32 - 1) { PFB(Ba) }  // loads (kt+1,ds0)
        offB += 1024;                       // -> (kt+1,ds1)
        STEP(Bb, 3)

        const unsigned kn0 = (unsigned)(kt * 2);
        const unsigned kn1 = kn0 + 1u;
        INSP(a00, a01, 0) INSP(a10, a11, 1)
        INSP(a20, a21, 2) INSP(a30, a31, 3)

        cv0 = cvn0; cv1 = cvn1;
    }

    // Quad butterfly: merge two sorted-2 (key,idx) lists per step.
#pragma unroll
    for (int m = 0; m < 4; ++m)
#pragma unroll
        for (int r = 0; r < 4; ++r) {
            unsigned k1 = b1[m * 4 + r], k2 = b2[m * 4 + r];
            int i1 = ((wave * 64 + (int)(k1 & 63u)) << 4) | l15;
            int i2 = ((wave * 64 + (int)(k2 & 63u)) << 4) | l15;
#pragma unroll
            for (int msk = 1; msk < 16; msk <<= 1) {
                unsigned ok1 = (unsigned)__shfl_xor((int)k1, msk, 64);
                int      oi1 = __shfl_xor(i1, msk, 64);
                unsigned ok2 = (unsigned)__shfl_xor((int)k2, msk, 64);
                int      oi2 = __shfl_xor(i2, msk, 64);
                bool ow = ok1 < k1;
                unsigned w1k = ow ? ok1 : k1; int w1i = ow ? oi1 : i1;
                unsigned lsk = ow ? k1 : ok1; int lsi = ow ? i1 : oi1;
                unsigned wsk = ow ? ok2 : k2; int wsi = ow ? oi2 : i2;
                bool sw = lsk < wsk;
                k1 = w1k; i1 = w1i;
                k2 = sw ? lsk : wsk; i2 = sw ? lsi : wsi;
            }
            if (l15 == 0) {
                int p = m * 16 + quad * 4 + r;
                r1K[wave][p] = k1; r1I[wave][p] = i1;
                r2K[wave][p] = k2; r2I[wave][p] = i2;
            }
        }
    __syncthreads();

    // ---- fused epilogue: cross-wave merge + exact fp64 rescore ----
    if (t < MB) {
        unsigned k1 = r1K[0][t], k2 = r2K[0][t];
        int      i1 = r1I[0][t], i2 = r2I[0][t];
#pragma unroll
        for (int w = 1; w < 4; ++w) {
            unsigned ok1 = r1K[w][t], ok2 = r2K[w][t];
            int      oi1 = r1I[w][t], oi2 = r2I[w][t];
            bool ow = ok1 < k1;
            unsigned w1k = ow ? ok1 : k1; int w1i = ow ? oi1 : i1;
            unsigned lsk = ow ? k1 : ok1; int lsi = ow ? i1 : oi1;
            unsigned wsk = ow ? ok2 : k2; int wsi = ow ? oi2 : i2;
            bool sw = lsk < wsk;
            k1 = w1k; i1 = w1i;
            k2 = sw ? lsk : wsk; i2 = sw ? lsi : wsi;
        }
        // Exact fp64 rescore of the two candidates (latent row is L2-hot;
        // coords is L3-resident). Tie -> smaller index.
        const float* x  = latent + (size_t)(row0 + t) * D_DIM;
        const float* ca = coords + (size_t)i1 * D_DIM;
        const float* cb = coords + (size_t)i2 * D_DIM;
        double d1 = 0.0, d2 = 0.0;
#pragma unroll
        for (int d = 0; d < D_DIM; d += 4) {
            float4 xv = *(const float4*)(x + d);
            float4 av = *(const float4*)(ca + d);
            float4 bv = *(const float4*)(cb + d);
            double e;
            e = (double)xv.x - (double)av.x; d1 += e * e;
            e = (double)xv.y - (double)av.y; d1 += e * e;
            e = (double)xv.z - (double)av.z; d1 += e * e;
            e = (double)xv.w - (double)av.w; d1 += e * e;
            e = (double)xv.x - (double)bv.x; d2 += e * e;
            e = (double)xv.y - (double)bv.y; d2 += e * e;
            e = (double)xv.z - (double)bv.z; d2 += e * e;
            e = (double)xv.w - (double)bv.w; d2 += e * e;
        }
        bool second = (d2 < d1) || (d2 == d1 && i2 < i1);
        out[row0 + t] = second ? i2 : i1;
    }
}

// ---------------------------------------------------------------------------
extern "C" void kernel_launch(void* const* d_in, const int* in_sizes, int n_in,
                              void* d_out, int out_size, void* d_ws, size_t ws_size,
                              hipStream_t stream) {
    const float* latent = (const float*)d_in[0];
    const float* coords = (const float*)d_in[1];
    int* out = (int*)d_out;

    // ws: chp [K*D] f16 | clp [K*D] f16 | c2b [K] f32
    f16*   chp = (f16*)d_ws;
    f16*   clp = chp + (size_t)K_CENT * D_DIM;
    float* c2b = (float*)(clp + (size_t)K_CENT * D_DIM);

    split_pack_c2<<<dim3(K_CENT * D_DIM / 256), dim3(256), 0, stream>>>(coords, chp, clp, c2b);
    argmin_mfma<<<dim3(N_PTS / MB), dim3(256), 0, stream>>>(latent, coords, chp, clp, c2b, out);
}